// Round 11
// baseline (680.593 us; speedup 1.0000x reference)
//
#include <hip/hip_runtime.h>
#include <hip/hip_bf16.h>
#include <math.h>

#define BB 16
#define NN 4096
#define SS 512
#define KK 32
#define CC 64
#define KCAP 2048

typedef _Float16 f16x8 __attribute__((ext_vector_type(8)));
typedef float f32x4 __attribute__((ext_vector_type(4)));

// ---------------------------------------------------------------------------
// Kernel 1: farthest point sampling, TWO INDEPENDENT BATCHES PER BLOCK.
// Per batch the structure is EXACTLY R5's (benched 363us/batch-serial):
// 8 waves, 8 pts/lane, lane-major, u64 (distbits<<32 | NN-1-p) DPP max chain,
// lane-63 b64 deposit, ONE barrier, b64 broadcast + 3-step DPP + readlane tail.
// The two batches' chains are independent: batch B's update/chain fills batch
// A's dependency bubbles, and the barrier+LDS-latency stall (the empirically
// un-shortenable ~half of each iteration) is paid ONCE for both batches.
// Replicates jnp: dist = ((dx*dx+dy*dy)+dz*dz), distance=min, argmax first-index.
// ---------------------------------------------------------------------------
template <int CTRL>
__device__ __forceinline__ unsigned long long dpp_umax64(unsigned long long k) {
  int lo = (int)(unsigned)(k & 0xFFFFFFFFull);
  int hi = (int)(unsigned)(k >> 32);
  int tlo = __builtin_amdgcn_update_dpp(lo, lo, CTRL, 0xF, 0xF, false);
  int thi = __builtin_amdgcn_update_dpp(hi, hi, CTRL, 0xF, 0xF, false);
  unsigned long long t = ((unsigned long long)(unsigned)thi << 32) | (unsigned)tlo;
  return t > k ? t : k;
}

__global__ __launch_bounds__(512) void fps_kernel(const float* __restrict__ xyz,
                                                  float* __restrict__ newxyz) {
#pragma clang fp contract(off)
  const int b0 = blockIdx.x * 2, tid = threadIdx.x;
  const int wid = tid >> 6, lane = tid & 63;
  __shared__ float sxA[NN], syA[NN], szA[NN];
  __shared__ float sxB[NN], syB[NN], szB[NN];
  __shared__ unsigned long long candA[2][8], candB[2][8];
  __shared__ int selA[SS], selB[SS];
  const float* baseA = xyz + (size_t)b0 * NN * 3;
  const float* baseB = xyz + (size_t)(b0 + 1) * NN * 3;
  for (int p = tid; p < NN; p += 512) {
    sxA[p] = baseA[3 * p + 0];
    syA[p] = baseA[3 * p + 1];
    szA[p] = baseA[3 * p + 2];
    sxB[p] = baseB[3 * p + 0];
    syB[p] = baseB[3 * p + 1];
    szB[p] = baseB[3 * p + 2];
  }
  if (tid == 0) { selA[0] = 0; selB[0] = 0; }
  __syncthreads();
  float pxA[8], pyA[8], pzA[8], dA[8];
  float pxB[8], pyB[8], pzB[8], dB[8];
#pragma unroll
  for (int j = 0; j < 8; j++) {
    int p = tid * 8 + j;
    pxA[j] = sxA[p]; pyA[j] = syA[p]; pzA[j] = szA[p]; dA[j] = 1e10f;
    pxB[j] = sxB[p]; pyB[j] = syB[p]; pzB[j] = szB[p]; dB[j] = 1e10f;
  }
  float cxA = sxA[0], cyA = syA[0], czA = szA[0];
  float cxB = sxB[0], cyB = syB[0], czB = szB[0];
  // Reference emits `farthest` BEFORE each update; 512 outputs need only 511
  // argmax steps (sel[0] = 0).
  for (int it = 0; it < SS - 1; it++) {
    // ---- batch A: update + in-lane argmax ----
    float bvA = -1.0f; int bjA = 0;
#pragma unroll
    for (int j = 0; j < 8; j++) {
      float dx = pxA[j] - cxA, dy = pyA[j] - cyA, dz = pzA[j] - czA;
      float t0 = dx * dx, t1 = dy * dy, t2 = dz * dz;
      float dd = (t0 + t1) + t2;
      float nd = fminf(dA[j], dd);
      dA[j] = nd;
      if (nd > bvA) { bvA = nd; bjA = j; }  // strict > keeps smallest j on ties
    }
    // ---- batch B: update + in-lane argmax (independent of A) ----
    float bvB = -1.0f; int bjB = 0;
#pragma unroll
    for (int j = 0; j < 8; j++) {
      float dx = pxB[j] - cxB, dy = pyB[j] - cyB, dz = pzB[j] - czB;
      float t0 = dx * dx, t1 = dy * dy, t2 = dz * dz;
      float dd = (t0 + t1) + t2;
      float nd = fminf(dB[j], dd);
      dB[j] = nd;
      if (nd > bvB) { bvB = nd; bjB = j; }
    }
    // pack: non-negative f32 bits are order-monotone; lo = NN-1-p so equal
    // distances pick the SMALLER point index (jnp.argmax first-match).
    unsigned long long keyA =
        ((unsigned long long)__float_as_uint(bvA) << 32) | (unsigned)(NN - 1 - (tid * 8 + bjA));
    unsigned long long keyB =
        ((unsigned long long)__float_as_uint(bvB) << 32) | (unsigned)(NN - 1 - (tid * 8 + bjB));
    // two independent DPP chains — scheduler interleaves them, hiding latency
    keyA = dpp_umax64<0x111>(keyA); keyB = dpp_umax64<0x111>(keyB);
    keyA = dpp_umax64<0x112>(keyA); keyB = dpp_umax64<0x112>(keyB);
    keyA = dpp_umax64<0x114>(keyA); keyB = dpp_umax64<0x114>(keyB);
    keyA = dpp_umax64<0x118>(keyA); keyB = dpp_umax64<0x118>(keyB);
    keyA = dpp_umax64<0x142>(keyA); keyB = dpp_umax64<0x142>(keyB);
    keyA = dpp_umax64<0x143>(keyA); keyB = dpp_umax64<0x143>(keyB);
    const int par = it & 1;
    if (lane == 63) {  // lane 63 holds each wave max
      candA[par][wid] = keyA;
      candB[par][wid] = keyB;
    }
    __syncthreads();
    // tails: broadcast b64 read + 3-step DPP + readlane, independent A/B
    unsigned long long kA = candA[par][lane & 7];
    unsigned long long kB = candB[par][lane & 7];
    kA = dpp_umax64<0x111>(kA); kB = dpp_umax64<0x111>(kB);
    kA = dpp_umax64<0x112>(kA); kB = dpp_umax64<0x112>(kB);
    kA = dpp_umax64<0x114>(kA); kB = dpp_umax64<0x114>(kB);
    const int loA = __builtin_amdgcn_readlane((int)(unsigned)(kA & 0xFFFFFFFFull), 7);
    const int loB = __builtin_amdgcn_readlane((int)(unsigned)(kB & 0xFFFFFFFFull), 7);
    const int curA = NN - 1 - loA;
    const int curB = NN - 1 - loB;
    cxA = sxA[curA]; cyA = syA[curA]; czA = szA[curA];
    cxB = sxB[curB]; cyB = syB[curB]; czB = szB[curB];
    if (tid == 0) { selA[it + 1] = curA; selB[it + 1] = curB; }
  }
  __syncthreads();
  for (int i = tid; i < SS * 3; i += 512) {
    int s = i / 3, c = i - s * 3;
    int gA = selA[s], gB = selB[s];
    float vA = (c == 0) ? sxA[gA] : (c == 1) ? syA[gA] : szA[gA];
    float vB = (c == 0) ? sxB[gB] : (c == 1) ? syB[gB] : szB[gB];
    newxyz[((size_t)b0 * SS + s) * 3 + c] = vA;
    newxyz[((size_t)(b0 + 1) * SS + s) * 3 + c] = vB;
  }
}

// ---------------------------------------------------------------------------
// Kernel 2: ball query. One block per (b,s) center, 256 threads, points loaded
// as 12 float4/thread. keys capped at KCAP=2048 (16KB LDS -> 8 blocks/CU);
// overflow (cnt>KCAP, ~impossible) handled by exact serial fallback which also
// covers the reference's NN-cnt<KK branch (cnt>4064 implies overflow).
// Replicates: d = ((-2*dot) + |c|^2) + |x|^2 ; mask = d > 0.04f.
// ---------------------------------------------------------------------------
__global__ __launch_bounds__(256) void ballq_kernel(const float* __restrict__ xyz,
                                                    const float* __restrict__ newxyz,
                                                    int* __restrict__ gidx) {
#pragma clang fp contract(off)
  const int bs = blockIdx.x;
  const int b = bs >> 9;
  const int tid = threadIdx.x;
  __shared__ unsigned long long keys[KCAP];
  __shared__ int s_cnt;
  __shared__ unsigned char inflag[64];
  __shared__ int outg[KK];
  __shared__ unsigned long long rk[4];
  __shared__ int rp[4];
  if (tid == 0) s_cnt = 0;
  __syncthreads();
  const float cx = newxyz[bs * 3 + 0];
  const float cy = newxyz[bs * 3 + 1];
  const float cz = newxyz[bs * 3 + 2];
  const float csq = (cx * cx + cy * cy) + cz * cz;
  const float* base = xyz + (size_t)b * NN * 3;
  const float R2 = 0.04f;
  float4 f[12];
  {
    const float4* b4 = reinterpret_cast<const float4*>(base) + tid * 12;
#pragma unroll
    for (int s = 0; s < 12; s++) f[s] = b4[s];
  }
#define BQ_ELEM(e) ((e & 3) == 0 ? f[(e) >> 2].x : (e & 3) == 1 ? f[(e) >> 2].y \
                  : (e & 3) == 2 ? f[(e) >> 2].z : f[(e) >> 2].w)
#pragma unroll
  for (int mIdx = 0; mIdx < 16; mIdx++) {
    const int p = tid * 16 + mIdx;
    float x = BQ_ELEM(3 * mIdx + 0);
    float y = BQ_ELEM(3 * mIdx + 1);
    float z = BQ_ELEM(3 * mIdx + 2);
    float dot = (cx * x + cy * y) + cz * z;
    float ssq = (x * x + y * y) + z * z;
    float dsq = ((-2.0f * dot) + csq) + ssq;
    bool in = !(dsq > R2);
    if (p < 64) inflag[p] = in ? (unsigned char)1 : (unsigned char)0;
    if (in) {
      int pos = atomicAdd(&s_cnt, 1);
      unsigned u = __float_as_uint(dsq);
      u ^= (u >> 31) ? 0xFFFFFFFFu : 0x80000000u;  // monotonic key
      if (pos < KCAP)
        keys[pos] = ((unsigned long long)u << 32) | (unsigned)p;
    }
  }
#undef BQ_ELEM
  __syncthreads();
  const int cnt = s_cnt;

  if (cnt > KCAP) {
    // exact serial fallback (~never taken); also covers NN-cnt<KK semantics
    if (tid == 0) {
      unsigned long long best[KK];
      for (int i = 0; i < KK; i++) best[i] = ~0ull;
      for (int p = 0; p < NN; p++) {
        float x = base[3 * p + 0], y = base[3 * p + 1], z = base[3 * p + 2];
        float dot = (cx * x + cy * y) + cz * z;
        float ssq = (x * x + y * y) + z * z;
        float dsq = ((-2.0f * dot) + csq) + ssq;
        if (!(dsq > R2)) {
          unsigned u = __float_as_uint(dsq);
          u ^= (u >> 31) ? 0xFFFFFFFFu : 0x80000000u;
          unsigned long long key = ((unsigned long long)u << 32) | (unsigned)p;
          if (key < best[KK - 1]) {
            int ins = KK - 1;
            while (ins > 0 && best[ins - 1] > key) { best[ins] = best[ins - 1]; ins--; }
            best[ins] = key;
          }
        }
      }
      if (NN - cnt < KK) {
        for (int i = 0; i < KK; i++) outg[i] = (int)(best[0] & 0xFFFFFFFFull);
      } else {
        for (int i = 0; i < KK; i++) outg[i] = (int)(best[i] & 0xFFFFFFFFull);
      }
    }
  } else if (cnt <= KK) {
    // fast path: all in-radius + lowest-index out-of-radius fill (first 64).
    if (tid < cnt && tid < KK) outg[tid] = (int)(keys[tid] & 0xFFFFFFFFull);
    if (tid == 0) {
      int pos = cnt;
      for (int i = 0; i < 64 && pos < KK; i++)
        if (!inflag[i]) outg[pos++] = i;
    }
  } else {
    // rare: more than 32 in radius -> 32 smallest (dist,idx) keys.
    for (int r = 0; r < KK; r++) {
      unsigned long long mk = ~0ull; int mp = -1;
      for (int i = tid; i < cnt; i += 256)
        if (keys[i] < mk) { mk = keys[i]; mp = i; }
      for (int off = 1; off < 64; off <<= 1) {
        unsigned long long ok = __shfl_xor(mk, off);
        int op = __shfl_xor(mp, off);
        if (ok < mk) { mk = ok; mp = op; }
      }
      if ((tid & 63) == 0) { rk[tid >> 6] = mk; rp[tid >> 6] = mp; }
      __syncthreads();
      if (tid == 0) {
        unsigned long long fm = rk[0]; int fp = rp[0];
        for (int i = 1; i < 4; i++) if (rk[i] < fm) { fm = rk[i]; fp = rp[i]; }
        outg[r] = (int)(fm & 0xFFFFFFFFull);
        keys[fp] = ~0ull;
      }
      __syncthreads();
    }
  }
  __syncthreads();
  if (tid < KK) gidx[(size_t)bs * KK + tid] = outg[tid];
}

// ---------------------------------------------------------------------------
// Kernel 3: gather + 3x (affine/BN-folded + ReLU) + maxpool via f16 MFMA.
// Block = 4 centers (128 k-rows), 256 thr (4 waves; wave w = center w).
// X layout: Xh[row][104] f16, cols 0..63 = feats (b64-aligned writes),
// 64..66 = centered xyz, 67..95 = zero k-pad. W layout: Wh[oc][104] f16
// (BN-scaled), same col permutation for layer 0.
// A-frag: row=lane&15, k=(lane>>4)*8+j ; B-frag: col(oc)=lane&15, same k;
// C/D: col=lane&15, row=(lane>>4)*4+reg (m89-verified).
// ---------------------------------------------------------------------------
__device__ __forceinline__ f32x4 mfma16(f16x8 a, f16x8 b, f32x4 c) {
  return __builtin_amdgcn_mfma_f32_16x16x32_f16(a, b, c, 0, 0, 0);
}

template <int KS, int NT, bool LAST>
__device__ __forceinline__ void mfma_layer(
    const int tid, _Float16 (*Xh)[104], _Float16 (*Wh)[104],
    float* sa, float* sbv, float (*mmp)[4],
    const float* __restrict__ w, const float* __restrict__ bb,
    const float* __restrict__ gg, const float* __restrict__ be,
    const float* __restrict__ rm, const float* __restrict__ rv,
    const int CIN, const bool permute_l0,
    float* __restrict__ out2, const int bs0) {
  constexpr int COUT = NT * 16;
  const int wid = tid >> 6, lane = tid & 63;
  const int w32 = wid * 32;
  if (tid < COUT) {
    float a = gg[tid] / sqrtf(rv[tid] + 1e-5f);
    sa[tid] = a;
    sbv[tid] = (bb[tid] - rm[tid]) * a + be[tid];
  }
  __syncthreads();  // sa ready; also previous Xh writes / gather complete
  for (int i = tid; i < COUT * CIN; i += 256) {
    int oc = i / CIN;
    int c = i - oc * CIN;
    int col = permute_l0 ? ((c < 3) ? 64 + c : c - 3) : c;
    Wh[oc][col] = (_Float16)(w[i] * sa[oc]);
  }
  __syncthreads();  // Wh + Xh ready
  f32x4 acc[2][NT];
#pragma unroll
  for (int mt = 0; mt < 2; mt++)
#pragma unroll
    for (int nt = 0; nt < NT; nt++) acc[mt][nt] = (f32x4){0.f, 0.f, 0.f, 0.f};
  const int r15 = lane & 15, kg = (lane >> 4) * 8;
#pragma unroll
  for (int ks = 0; ks < KS; ks++) {
    const int kk = ks * 32 + kg;
    f16x8 a0 = *(const f16x8*)&Xh[w32 + r15][kk];
    f16x8 a1 = *(const f16x8*)&Xh[w32 + 16 + r15][kk];
#pragma unroll
    for (int nt = 0; nt < NT; nt++) {
      f16x8 bf = *(const f16x8*)&Wh[nt * 16 + r15][kk];
      acc[0][nt] = mfma16(a0, bf, acc[0][nt]);
      acc[1][nt] = mfma16(a1, bf, acc[1][nt]);
    }
  }
  __syncthreads();  // all LDS reads done before overwrite
  if constexpr (!LAST) {
#pragma unroll
    for (int nt = 0; nt < NT; nt++) {
      const int col = nt * 16 + r15;
      const float bias = sbv[col];
#pragma unroll
      for (int mt = 0; mt < 2; mt++)
#pragma unroll
        for (int r = 0; r < 4; r++) {
          const int row = w32 + mt * 16 + (lane >> 4) * 4 + r;
          Xh[row][col] = (_Float16)fmaxf(acc[mt][nt][r] + bias, 0.0f);
        }
    }
    // no barrier needed here: next layer's first barrier covers these writes
  } else {
#pragma unroll
    for (int nt = 0; nt < NT; nt++) {
      const int col = nt * 16 + r15;
      const float bias = sbv[col];
      float mx = 0.0f;  // relu outputs >= 0
#pragma unroll
      for (int mt = 0; mt < 2; mt++)
#pragma unroll
        for (int r = 0; r < 4; r++)
          mx = fmaxf(mx, fmaxf(acc[mt][nt][r] + bias, 0.0f));
      mmp[wid * 128 + col][lane >> 4] = mx;
    }
    __syncthreads();
    for (int e = tid; e < 4 * 128; e += 256) {
      float m = fmaxf(fmaxf(mmp[e][0], mmp[e][1]), fmaxf(mmp[e][2], mmp[e][3]));
      out2[((size_t)(bs0 + (e >> 7))) * 128 + (e & 127)] = m;
    }
  }
}

__global__ __launch_bounds__(256, 2) void mlp_kernel(
    const float* __restrict__ xyz, const float* __restrict__ points,
    const float* __restrict__ newxyz, const int* __restrict__ gidx,
    const float* __restrict__ w0, const float* __restrict__ b0,
    const float* __restrict__ g0, const float* __restrict__ be0,
    const float* __restrict__ rm0, const float* __restrict__ rv0,
    const float* __restrict__ w1, const float* __restrict__ b1,
    const float* __restrict__ g1, const float* __restrict__ be1,
    const float* __restrict__ rm1, const float* __restrict__ rv1,
    const float* __restrict__ w2, const float* __restrict__ b2,
    const float* __restrict__ g2, const float* __restrict__ be2,
    const float* __restrict__ rm2, const float* __restrict__ rv2,
    float* __restrict__ out2) {
  const int tid = threadIdx.x;
  const int bs0 = blockIdx.x * 4;
  const int b = bs0 >> 9;
  __shared__ _Float16 Xh[128][104];
  __shared__ _Float16 Wh[128][104];
  __shared__ float sa[128], sbv[128];
  __shared__ float mmp[512][4];
  __shared__ int sg[128];
  if (tid < 128) sg[tid] = gidx[(size_t)bs0 * KK + tid];
  __syncthreads();
  // gather point features -> f16 cols 0..63 (aligned b64 writes)
  for (int i = tid; i < 128 * 16; i += 256) {
    int r = i >> 4, c4 = i & 15;
    float4 v = *reinterpret_cast<const float4*>(
        &points[((size_t)b * NN + sg[r]) * CC + c4 * 4]);
    _Float16* dst = &Xh[r][c4 * 4];
    dst[0] = (_Float16)v.x; dst[1] = (_Float16)v.y;
    dst[2] = (_Float16)v.z; dst[3] = (_Float16)v.w;
  }
  // centered xyz -> cols 64..66 ; zero k-pad cols 67..95 (disjoint, no race)
  if (tid < 128) {
    int ci = tid >> 5;
    int g = sg[tid];
    const float* cp = newxyz + ((size_t)bs0 + ci) * 3;
    const float* pp = xyz + ((size_t)b * NN + g) * 3;
    Xh[tid][64] = (_Float16)(pp[0] - cp[0]);
    Xh[tid][65] = (_Float16)(pp[1] - cp[1]);
    Xh[tid][66] = (_Float16)(pp[2] - cp[2]);
  }
  for (int i = tid; i < 128 * 29; i += 256) {
    int r = i / 29, c = 67 + i % 29;
    Xh[r][c] = (_Float16)0.0f;
    if (r < 64) Wh[r][c] = (_Float16)0.0f;  // W k-pad for layer 0
  }
  // layers (first barrier inside mfma_layer covers the writes above)
  mfma_layer<3, 4, false>(tid, Xh, Wh, sa, sbv, mmp, w0, b0, g0, be0, rm0, rv0,
                          67, true, nullptr, bs0);
  mfma_layer<2, 4, false>(tid, Xh, Wh, sa, sbv, mmp, w1, b1, g1, be1, rm1, rv1,
                          64, false, nullptr, bs0);
  mfma_layer<2, 8, true>(tid, Xh, Wh, sa, sbv, mmp, w2, b2, g2, be2, rm2, rv2,
                         64, false, out2, bs0);
}

// ---------------------------------------------------------------------------
extern "C" void kernel_launch(void* const* d_in, const int* in_sizes, int n_in,
                              void* d_out, int out_size, void* d_ws, size_t ws_size,
                              hipStream_t stream) {
  const float* xyz = (const float*)d_in[0];
  const float* points = (const float*)d_in[1];
  const float* w0 = (const float*)d_in[2];
  const float* b0 = (const float*)d_in[3];
  const float* g0 = (const float*)d_in[4];
  const float* be0 = (const float*)d_in[5];
  const float* rm0 = (const float*)d_in[6];
  const float* rv0 = (const float*)d_in[7];
  const float* w1 = (const float*)d_in[8];
  const float* b1 = (const float*)d_in[9];
  const float* g1 = (const float*)d_in[10];
  const float* be1 = (const float*)d_in[11];
  const float* rm1 = (const float*)d_in[12];
  const float* rv1 = (const float*)d_in[13];
  const float* w2 = (const float*)d_in[14];
  const float* b2 = (const float*)d_in[15];
  const float* g2 = (const float*)d_in[16];
  const float* be2 = (const float*)d_in[17];
  const float* rm2 = (const float*)d_in[18];
  const float* rv2 = (const float*)d_in[19];

  float* newxyz = (float*)d_out;                       // (B, 512, 3)
  float* out2 = (float*)d_out + (size_t)BB * SS * 3;   // (B, 512, 128)
  int* gidx = (int*)d_ws;                              // (B, 512, 32)

  fps_kernel<<<BB / 2, 512, 0, stream>>>(xyz, newxyz);
  ballq_kernel<<<BB * SS, 256, 0, stream>>>(xyz, newxyz, gidx);
  mlp_kernel<<<(BB * SS) / 4, 256, 0, stream>>>(
      xyz, points, newxyz, gidx,
      w0, b0, g0, be0, rm0, rv0,
      w1, b1, g1, be1, rm1, rv1,
      w2, b2, g2, be2, rm2, rv2,
      out2);
}

// Round 12
// 431.161 us; speedup vs baseline: 1.5785x; 1.5785x over previous
//
#include <hip/hip_runtime.h>
#include <hip/hip_bf16.h>
#include <math.h>

#define BB 16
#define NN 4096
#define SS 512
#define KK 32
#define CC 64
#define KCAP 2048

typedef _Float16 f16x8 __attribute__((ext_vector_type(8)));
typedef float f32x4 __attribute__((ext_vector_type(4)));
typedef float f32x2 __attribute__((ext_vector_type(2)));

// ---------------------------------------------------------------------------
// Kernel 1: farthest point sampling — R5/R9 structure (benched 363us), with the
// distance-update arithmetic in PACKED FP32 (v_pk_add/mul via float2 vectors,
// ~40 instr vs 72 scalar; per-slot IEEE-identical so selection is bit-exact).
// 8 waves, 8 pts/lane, lane-major (p = tid*8+j). u64-packed
// (distbits<<32 | NN-1-p) DPP max chain; lane 63 deposits the wave key; ONE
// barrier; post-barrier b64 broadcast read + 3-step DPP + readlane tail.
// Tie semantics = jnp argmax first-index (smallest j via descending rescan,
// smallest p via NN-1-p in the key). Parity double-buffered slots.
// Replicates jnp: dist = ((dx*dx+dy*dy)+dz*dz), distance=min, argmax first-index.
// ---------------------------------------------------------------------------
template <int CTRL>
__device__ __forceinline__ unsigned long long dpp_umax64(unsigned long long k) {
  int lo = (int)(unsigned)(k & 0xFFFFFFFFull);
  int hi = (int)(unsigned)(k >> 32);
  int tlo = __builtin_amdgcn_update_dpp(lo, lo, CTRL, 0xF, 0xF, false);
  int thi = __builtin_amdgcn_update_dpp(hi, hi, CTRL, 0xF, 0xF, false);
  unsigned long long t = ((unsigned long long)(unsigned)thi << 32) | (unsigned)tlo;
  return t > k ? t : k;
}

__global__ __launch_bounds__(512) void fps_kernel(const float* __restrict__ xyz,
                                                  float* __restrict__ newxyz) {
#pragma clang fp contract(off)
  const int b = blockIdx.x, tid = threadIdx.x;
  const int wid = tid >> 6, lane = tid & 63;
  __shared__ float sx[NN], sy[NN], sz[NN];
  __shared__ unsigned long long cand[2][8];
  __shared__ int sel[SS];
  const float* base = xyz + (size_t)b * NN * 3;
  for (int p = tid; p < NN; p += 512) {
    sx[p] = base[3 * p + 0];
    sy[p] = base[3 * p + 1];
    sz[p] = base[3 * p + 2];
  }
  if (tid == 0) sel[0] = 0;
  __syncthreads();
  // 8 points per lane as 4 float2 pairs (j = 2q + s), lane-major p = tid*8+j
  f32x2 px2[4], py2[4], pz2[4], d2[4];
#pragma unroll
  for (int q = 0; q < 4; q++) {
    int p = tid * 8 + 2 * q;
    px2[q] = (f32x2){sx[p], sx[p + 1]};
    py2[q] = (f32x2){sy[p], sy[p + 1]};
    pz2[q] = (f32x2){sz[p], sz[p + 1]};
    d2[q] = (f32x2){1e10f, 1e10f};
  }
  float cx = sx[0], cy = sy[0], cz = sz[0];
  // Reference emits `farthest` BEFORE each update; 512 outputs need only 511
  // argmax steps (sel[0] = 0).
  for (int it = 0; it < SS - 1; it++) {
    const f32x2 cX = (f32x2){cx, cx};
    const f32x2 cY = (f32x2){cy, cy};
    const f32x2 cZ = (f32x2){cz, cz};
    f32x2 mx2 = (f32x2){-1.0f, -1.0f};
#pragma unroll
    for (int q = 0; q < 4; q++) {
      f32x2 dx = px2[q] - cX, dy = py2[q] - cY, dz = pz2[q] - cZ;
      f32x2 t0 = dx * dx, t1 = dy * dy, t2 = dz * dz;
      f32x2 dd = (t0 + t1) + t2;
      f32x2 nd = __builtin_elementwise_min(d2[q], dd);
      d2[q] = nd;
      mx2 = __builtin_elementwise_max(mx2, nd);
    }
    const float bv = fmaxf(mx2.x, mx2.y);
    // descending rescan with constant indices: smallest j achieving bv wins
    int bj = 7;
    if (d2[3].x == bv) bj = 6;
    if (d2[2].y == bv) bj = 5;
    if (d2[2].x == bv) bj = 4;
    if (d2[1].y == bv) bj = 3;
    if (d2[1].x == bv) bj = 2;
    if (d2[0].y == bv) bj = 1;
    if (d2[0].x == bv) bj = 0;
    const int bp = tid * 8 + bj;
    // pack: non-negative f32 bits are order-monotone; lo = NN-1-p so equal
    // distances pick the SMALLER point index (jnp.argmax first-match).
    unsigned long long key =
        ((unsigned long long)__float_as_uint(bv) << 32) | (unsigned)(NN - 1 - bp);
    key = dpp_umax64<0x111>(key);  // row_shr:1
    key = dpp_umax64<0x112>(key);  // row_shr:2
    key = dpp_umax64<0x114>(key);  // row_shr:4
    key = dpp_umax64<0x118>(key);  // row_shr:8
    key = dpp_umax64<0x142>(key);  // row_bcast:15
    key = dpp_umax64<0x143>(key);  // row_bcast:31
    const int par = it & 1;
    if (lane == 63) cand[par][wid] = key;  // lane 63 holds the wave max
    __syncthreads();
    // every lane reads one of the 8 wave keys (broadcast groups), 3-step DPP
    // max within lanes 0..7 -> lane 7 holds the block max
    unsigned long long k = cand[par][lane & 7];
    k = dpp_umax64<0x111>(k);
    k = dpp_umax64<0x112>(k);
    k = dpp_umax64<0x114>(k);
    const int lo = __builtin_amdgcn_readlane((int)(unsigned)(k & 0xFFFFFFFFull), 7);
    const int cur = NN - 1 - lo;
    cx = sx[cur]; cy = sy[cur]; cz = sz[cur];
    if (tid == 0) sel[it + 1] = cur;
  }
  __syncthreads();
  for (int i = tid; i < SS * 3; i += 512) {
    int s = i / 3, c = i - s * 3;
    int g = sel[s];
    float v = (c == 0) ? sx[g] : (c == 1) ? sy[g] : sz[g];
    newxyz[((size_t)b * SS + s) * 3 + c] = v;
  }
}

// ---------------------------------------------------------------------------
// Kernel 2: ball query. One block per (b,s) center, 256 threads, points loaded
// as 12 float4/thread. keys capped at KCAP=2048 (16KB LDS -> 8 blocks/CU);
// overflow (cnt>KCAP, ~impossible) handled by exact serial fallback which also
// covers the reference's NN-cnt<KK branch (cnt>4064 implies overflow).
// Replicates: d = ((-2*dot) + |c|^2) + |x|^2 ; mask = d > 0.04f.
// ---------------------------------------------------------------------------
__global__ __launch_bounds__(256) void ballq_kernel(const float* __restrict__ xyz,
                                                    const float* __restrict__ newxyz,
                                                    int* __restrict__ gidx) {
#pragma clang fp contract(off)
  const int bs = blockIdx.x;
  const int b = bs >> 9;
  const int tid = threadIdx.x;
  __shared__ unsigned long long keys[KCAP];
  __shared__ int s_cnt;
  __shared__ unsigned char inflag[64];
  __shared__ int outg[KK];
  __shared__ unsigned long long rk[4];
  __shared__ int rp[4];
  if (tid == 0) s_cnt = 0;
  __syncthreads();
  const float cx = newxyz[bs * 3 + 0];
  const float cy = newxyz[bs * 3 + 1];
  const float cz = newxyz[bs * 3 + 2];
  const float csq = (cx * cx + cy * cy) + cz * cz;
  const float* base = xyz + (size_t)b * NN * 3;
  const float R2 = 0.04f;
  float4 f[12];
  {
    const float4* b4 = reinterpret_cast<const float4*>(base) + tid * 12;
#pragma unroll
    for (int s = 0; s < 12; s++) f[s] = b4[s];
  }
#define BQ_ELEM(e) ((e & 3) == 0 ? f[(e) >> 2].x : (e & 3) == 1 ? f[(e) >> 2].y \
                  : (e & 3) == 2 ? f[(e) >> 2].z : f[(e) >> 2].w)
#pragma unroll
  for (int mIdx = 0; mIdx < 16; mIdx++) {
    const int p = tid * 16 + mIdx;
    float x = BQ_ELEM(3 * mIdx + 0);
    float y = BQ_ELEM(3 * mIdx + 1);
    float z = BQ_ELEM(3 * mIdx + 2);
    float dot = (cx * x + cy * y) + cz * z;
    float ssq = (x * x + y * y) + z * z;
    float dsq = ((-2.0f * dot) + csq) + ssq;
    bool in = !(dsq > R2);
    if (p < 64) inflag[p] = in ? (unsigned char)1 : (unsigned char)0;
    if (in) {
      int pos = atomicAdd(&s_cnt, 1);
      unsigned u = __float_as_uint(dsq);
      u ^= (u >> 31) ? 0xFFFFFFFFu : 0x80000000u;  // monotonic key
      if (pos < KCAP)
        keys[pos] = ((unsigned long long)u << 32) | (unsigned)p;
    }
  }
#undef BQ_ELEM
  __syncthreads();
  const int cnt = s_cnt;

  if (cnt > KCAP) {
    // exact serial fallback (~never taken); also covers NN-cnt<KK semantics
    if (tid == 0) {
      unsigned long long best[KK];
      for (int i = 0; i < KK; i++) best[i] = ~0ull;
      for (int p = 0; p < NN; p++) {
        float x = base[3 * p + 0], y = base[3 * p + 1], z = base[3 * p + 2];
        float dot = (cx * x + cy * y) + cz * z;
        float ssq = (x * x + y * y) + z * z;
        float dsq = ((-2.0f * dot) + csq) + ssq;
        if (!(dsq > R2)) {
          unsigned u = __float_as_uint(dsq);
          u ^= (u >> 31) ? 0xFFFFFFFFu : 0x80000000u;
          unsigned long long key = ((unsigned long long)u << 32) | (unsigned)p;
          if (key < best[KK - 1]) {
            int ins = KK - 1;
            while (ins > 0 && best[ins - 1] > key) { best[ins] = best[ins - 1]; ins--; }
            best[ins] = key;
          }
        }
      }
      if (NN - cnt < KK) {
        for (int i = 0; i < KK; i++) outg[i] = (int)(best[0] & 0xFFFFFFFFull);
      } else {
        for (int i = 0; i < KK; i++) outg[i] = (int)(best[i] & 0xFFFFFFFFull);
      }
    }
  } else if (cnt <= KK) {
    // fast path: all in-radius + lowest-index out-of-radius fill (first 64).
    if (tid < cnt && tid < KK) outg[tid] = (int)(keys[tid] & 0xFFFFFFFFull);
    if (tid == 0) {
      int pos = cnt;
      for (int i = 0; i < 64 && pos < KK; i++)
        if (!inflag[i]) outg[pos++] = i;
    }
  } else {
    // rare: more than 32 in radius -> 32 smallest (dist,idx) keys.
    for (int r = 0; r < KK; r++) {
      unsigned long long mk = ~0ull; int mp = -1;
      for (int i = tid; i < cnt; i += 256)
        if (keys[i] < mk) { mk = keys[i]; mp = i; }
      for (int off = 1; off < 64; off <<= 1) {
        unsigned long long ok = __shfl_xor(mk, off);
        int op = __shfl_xor(mp, off);
        if (ok < mk) { mk = ok; mp = op; }
      }
      if ((tid & 63) == 0) { rk[tid >> 6] = mk; rp[tid >> 6] = mp; }
      __syncthreads();
      if (tid == 0) {
        unsigned long long fm = rk[0]; int fp = rp[0];
        for (int i = 1; i < 4; i++) if (rk[i] < fm) { fm = rk[i]; fp = rp[i]; }
        outg[r] = (int)(fm & 0xFFFFFFFFull);
        keys[fp] = ~0ull;
      }
      __syncthreads();
    }
  }
  __syncthreads();
  if (tid < KK) gidx[(size_t)bs * KK + tid] = outg[tid];
}

// ---------------------------------------------------------------------------
// Kernel 3: gather + 3x (affine/BN-folded + ReLU) + maxpool via f16 MFMA.
// Block = 4 centers (128 k-rows), 256 thr (4 waves; wave w = center w).
// X layout: Xh[row][104] f16, cols 0..63 = feats (b64-aligned writes),
// 64..66 = centered xyz, 67..95 = zero k-pad. W layout: Wh[oc][104] f16
// (BN-scaled), same col permutation for layer 0.
// A-frag: row=lane&15, k=(lane>>4)*8+j ; B-frag: col(oc)=lane&15, same k;
// C/D: col=lane&15, row=(lane>>4)*4+reg (m89-verified).
// ---------------------------------------------------------------------------
__device__ __forceinline__ f32x4 mfma16(f16x8 a, f16x8 b, f32x4 c) {
  return __builtin_amdgcn_mfma_f32_16x16x32_f16(a, b, c, 0, 0, 0);
}

template <int KS, int NT, bool LAST>
__device__ __forceinline__ void mfma_layer(
    const int tid, _Float16 (*Xh)[104], _Float16 (*Wh)[104],
    float* sa, float* sbv, float (*mmp)[4],
    const float* __restrict__ w, const float* __restrict__ bb,
    const float* __restrict__ gg, const float* __restrict__ be,
    const float* __restrict__ rm, const float* __restrict__ rv,
    const int CIN, const bool permute_l0,
    float* __restrict__ out2, const int bs0) {
  constexpr int COUT = NT * 16;
  const int wid = tid >> 6, lane = tid & 63;
  const int w32 = wid * 32;
  if (tid < COUT) {
    float a = gg[tid] / sqrtf(rv[tid] + 1e-5f);
    sa[tid] = a;
    sbv[tid] = (bb[tid] - rm[tid]) * a + be[tid];
  }
  __syncthreads();  // sa ready; also previous Xh writes / gather complete
  for (int i = tid; i < COUT * CIN; i += 256) {
    int oc = i / CIN;
    int c = i - oc * CIN;
    int col = permute_l0 ? ((c < 3) ? 64 + c : c - 3) : c;
    Wh[oc][col] = (_Float16)(w[i] * sa[oc]);
  }
  __syncthreads();  // Wh + Xh ready
  f32x4 acc[2][NT];
#pragma unroll
  for (int mt = 0; mt < 2; mt++)
#pragma unroll
    for (int nt = 0; nt < NT; nt++) acc[mt][nt] = (f32x4){0.f, 0.f, 0.f, 0.f};
  const int r15 = lane & 15, kg = (lane >> 4) * 8;
#pragma unroll
  for (int ks = 0; ks < KS; ks++) {
    const int kk = ks * 32 + kg;
    f16x8 a0 = *(const f16x8*)&Xh[w32 + r15][kk];
    f16x8 a1 = *(const f16x8*)&Xh[w32 + 16 + r15][kk];
#pragma unroll
    for (int nt = 0; nt < NT; nt++) {
      f16x8 bf = *(const f16x8*)&Wh[nt * 16 + r15][kk];
      acc[0][nt] = mfma16(a0, bf, acc[0][nt]);
      acc[1][nt] = mfma16(a1, bf, acc[1][nt]);
    }
  }
  __syncthreads();  // all LDS reads done before overwrite
  if constexpr (!LAST) {
#pragma unroll
    for (int nt = 0; nt < NT; nt++) {
      const int col = nt * 16 + r15;
      const float bias = sbv[col];
#pragma unroll
      for (int mt = 0; mt < 2; mt++)
#pragma unroll
        for (int r = 0; r < 4; r++) {
          const int row = w32 + mt * 16 + (lane >> 4) * 4 + r;
          Xh[row][col] = (_Float16)fmaxf(acc[mt][nt][r] + bias, 0.0f);
        }
    }
    // no barrier needed here: next layer's first barrier covers these writes
  } else {
#pragma unroll
    for (int nt = 0; nt < NT; nt++) {
      const int col = nt * 16 + r15;
      const float bias = sbv[col];
      float mx = 0.0f;  // relu outputs >= 0
#pragma unroll
      for (int mt = 0; mt < 2; mt++)
#pragma unroll
        for (int r = 0; r < 4; r++)
          mx = fmaxf(mx, fmaxf(acc[mt][nt][r] + bias, 0.0f));
      mmp[wid * 128 + col][lane >> 4] = mx;
    }
    __syncthreads();
    for (int e = tid; e < 4 * 128; e += 256) {
      float m = fmaxf(fmaxf(mmp[e][0], mmp[e][1]), fmaxf(mmp[e][2], mmp[e][3]));
      out2[((size_t)(bs0 + (e >> 7))) * 128 + (e & 127)] = m;
    }
  }
}

__global__ __launch_bounds__(256, 2) void mlp_kernel(
    const float* __restrict__ xyz, const float* __restrict__ points,
    const float* __restrict__ newxyz, const int* __restrict__ gidx,
    const float* __restrict__ w0, const float* __restrict__ b0,
    const float* __restrict__ g0, const float* __restrict__ be0,
    const float* __restrict__ rm0, const float* __restrict__ rv0,
    const float* __restrict__ w1, const float* __restrict__ b1,
    const float* __restrict__ g1, const float* __restrict__ be1,
    const float* __restrict__ rm1, const float* __restrict__ rv1,
    const float* __restrict__ w2, const float* __restrict__ b2,
    const float* __restrict__ g2, const float* __restrict__ be2,
    const float* __restrict__ rm2, const float* __restrict__ rv2,
    float* __restrict__ out2) {
  const int tid = threadIdx.x;
  const int bs0 = blockIdx.x * 4;
  const int b = bs0 >> 9;
  __shared__ _Float16 Xh[128][104];
  __shared__ _Float16 Wh[128][104];
  __shared__ float sa[128], sbv[128];
  __shared__ float mmp[512][4];
  __shared__ int sg[128];
  if (tid < 128) sg[tid] = gidx[(size_t)bs0 * KK + tid];
  __syncthreads();
  // gather point features -> f16 cols 0..63 (aligned b64 writes)
  for (int i = tid; i < 128 * 16; i += 256) {
    int r = i >> 4, c4 = i & 15;
    float4 v = *reinterpret_cast<const float4*>(
        &points[((size_t)b * NN + sg[r]) * CC + c4 * 4]);
    _Float16* dst = &Xh[r][c4 * 4];
    dst[0] = (_Float16)v.x; dst[1] = (_Float16)v.y;
    dst[2] = (_Float16)v.z; dst[3] = (_Float16)v.w;
  }
  // centered xyz -> cols 64..66 ; zero k-pad cols 67..95 (disjoint, no race)
  if (tid < 128) {
    int ci = tid >> 5;
    int g = sg[tid];
    const float* cp = newxyz + ((size_t)bs0 + ci) * 3;
    const float* pp = xyz + ((size_t)b * NN + g) * 3;
    Xh[tid][64] = (_Float16)(pp[0] - cp[0]);
    Xh[tid][65] = (_Float16)(pp[1] - cp[1]);
    Xh[tid][66] = (_Float16)(pp[2] - cp[2]);
  }
  for (int i = tid; i < 128 * 29; i += 256) {
    int r = i / 29, c = 67 + i % 29;
    Xh[r][c] = (_Float16)0.0f;
    if (r < 64) Wh[r][c] = (_Float16)0.0f;  // W k-pad for layer 0
  }
  // layers (first barrier inside mfma_layer covers the writes above)
  mfma_layer<3, 4, false>(tid, Xh, Wh, sa, sbv, mmp, w0, b0, g0, be0, rm0, rv0,
                          67, true, nullptr, bs0);
  mfma_layer<2, 4, false>(tid, Xh, Wh, sa, sbv, mmp, w1, b1, g1, be1, rm1, rv1,
                          64, false, nullptr, bs0);
  mfma_layer<2, 8, true>(tid, Xh, Wh, sa, sbv, mmp, w2, b2, g2, be2, rm2, rv2,
                         64, false, out2, bs0);
}

// ---------------------------------------------------------------------------
extern "C" void kernel_launch(void* const* d_in, const int* in_sizes, int n_in,
                              void* d_out, int out_size, void* d_ws, size_t ws_size,
                              hipStream_t stream) {
  const float* xyz = (const float*)d_in[0];
  const float* points = (const float*)d_in[1];
  const float* w0 = (const float*)d_in[2];
  const float* b0 = (const float*)d_in[3];
  const float* g0 = (const float*)d_in[4];
  const float* be0 = (const float*)d_in[5];
  const float* rm0 = (const float*)d_in[6];
  const float* rv0 = (const float*)d_in[7];
  const float* w1 = (const float*)d_in[8];
  const float* b1 = (const float*)d_in[9];
  const float* g1 = (const float*)d_in[10];
  const float* be1 = (const float*)d_in[11];
  const float* rm1 = (const float*)d_in[12];
  const float* rv1 = (const float*)d_in[13];
  const float* w2 = (const float*)d_in[14];
  const float* b2 = (const float*)d_in[15];
  const float* g2 = (const float*)d_in[16];
  const float* be2 = (const float*)d_in[17];
  const float* rm2 = (const float*)d_in[18];
  const float* rv2 = (const float*)d_in[19];

  float* newxyz = (float*)d_out;                       // (B, 512, 3)
  float* out2 = (float*)d_out + (size_t)BB * SS * 3;   // (B, 512, 128)
  int* gidx = (int*)d_ws;                              // (B, 512, 32)

  fps_kernel<<<BB, 512, 0, stream>>>(xyz, newxyz);
  ballq_kernel<<<BB * SS, 256, 0, stream>>>(xyz, newxyz, gidx);
  mlp_kernel<<<(BB * SS) / 4, 256, 0, stream>>>(
      xyz, points, newxyz, gidx,
      w0, b0, g0, be0, rm0, rv0,
      w1, b1, g1, be1, rm1, rv1,
      w2, b2, g2, be2, rm2, rv2,
      out2);
}